// Round 8
// baseline (101.114 us; speedup 1.0000x reference)
//
#include <hip/hip_runtime.h>
#include <hip/hip_fp16.h>
#include <math.h>

// Problem constants (reference: B=8, N=16384, K=32)
#define PB 8
#define PN 16384
#define PK 32
#define PEPS 1e-5f

// pack three floats into {h2(a,b), h2(c,0)}
__device__ __forceinline__ uint2 pack3(float a, float b, float c) {
    union { __half2 h2[2]; uint2 u; } r;
    r.h2[0] = __halves2half2(__float2half_rn(a), __float2half_rn(b));
    r.h2[1] = __halves2half2(__float2half_rn(c), __float2half_rn(0.f));
    return r.u;
}
__device__ __forceinline__ unsigned packh2(float a, float b) {
    union { __half2 h2; unsigned u; } r;
    r.h2 = __halves2half2(__float2half_rn(a), __float2half_rn(b));
    return r.u;
}

// Single fused kernel. 256 blocks x 512 threads, 1 WG/CU (128 KiB LDS).
// XCD swizzle: batch = blockIdx & 7 -> with round-robin block->XCD dispatch,
// all 32 blocks of a batch land on one XCD, making the batch's 384 KB record
// set L2-resident (read once from HBM, reused 31x at L2 speed).
// Phase 1: stage whole batch xyz (fp32->fp16, 128 KiB LDS), compute all 32
//          softmax numerators e_k per thread straight-line.
// Phase 2: restage same LDS with intensity (prefetched + pre-packed during
//          phase 1), accumulate sum e_k * i_k.
// Logits are bounded by the tiny folded weights -> no max-subtraction
// (validated rounds 5-7).
__global__ __launch_bounds__(512, 1) void sa_fused(
    const float* __restrict__ xyz,        // [B,N,3]
    const float* __restrict__ intensity,  // [B,3,N]
    const int*   __restrict__ indices,    // [B,N,K]
    const float* __restrict__ w1, const float* __restrict__ b1,
    const float* __restrict__ gamma_, const float* __restrict__ beta_,
    const float* __restrict__ mean_, const float* __restrict__ var_,
    const float* __restrict__ w2, const float* __restrict__ b2,
    float* __restrict__ out)              // [B,3,N]
{
    __shared__ uint4 sbuf[PN / 2];        // 128 KiB, one operand for the batch
    const uint2* sx = (const uint2*)sbuf;

    const int tid   = threadIdx.x;
    const int b     = blockIdx.x & 7;     // XCD-pinned batch
    const int chunk = blockIdx.x >> 3;    // 0..31 within batch
    const int n     = chunk * 512 + tid;  // point within batch
    const int q     = (b << 14) + n;      // global point id

    // fold BN into affine (uniform VALU, once per thread)
    const float sc0 = gamma_[0] * rsqrtf(var_[0] + PEPS);
    const float sc1 = gamma_[1] * rsqrtf(var_[1] + PEPS);
    const float sc2 = gamma_[2] * rsqrtf(var_[2] + PEPS);
    const float A00 = w1[0] * sc0, A01 = w1[1] * sc0, A02 = w1[2] * sc0;
    const float A10 = w1[3] * sc1, A11 = w1[4] * sc1, A12 = w1[5] * sc1;
    const float A20 = w1[6] * sc2, A21 = w1[7] * sc2, A22 = w1[8] * sc2;
    const float d0 = (b1[0] - mean_[0]) * sc0 + beta_[0];
    const float d1 = (b1[1] - mean_[1]) * sc1 + beta_[1];
    const float d2 = (b1[2] - mean_[2]) * sc2 + beta_[2];
    const float w0 = w2[0], w1v = w2[1], w2v = w2[2];
    const float bias2 = b2[0];

    // center xyz in fp32 (exact)
    const float cx = xyz[3 * (size_t)q + 0];
    const float cy = xyz[3 * (size_t)q + 1];
    const float cz = xyz[3 * (size_t)q + 2];

    // all 32 neighbor indices (coalesced int4 loads)
    int idxs[32];
    {
        const int4* ip = (const int4*)(indices + (size_t)q * PK);
#pragma unroll
        for (int j = 0; j < 8; ++j) {
            const int4 v = ip[j];
            idxs[4 * j + 0] = v.x; idxs[4 * j + 1] = v.y;
            idxs[4 * j + 2] = v.z; idxs[4 * j + 3] = v.w;
        }
    }

    // ---- stage 1: batch xyz fp32 -> fp16 LDS (3 float4 = 4 points) ----
    {
        const float4* xv = (const float4*)(xyz + (size_t)b * PN * 3);
#pragma unroll
        for (int j = 0; j < 8; ++j) {
            const int m = tid + j * 512;          // 0..4095 (4 points each)
            const float4 f0 = xv[3 * m + 0];
            const float4 f1 = xv[3 * m + 1];
            const float4 f2 = xv[3 * m + 2];
            union { uint2 u2[4]; uint4 u4[2]; } pk;
            pk.u2[0] = pack3(f0.x, f0.y, f0.z);
            pk.u2[1] = pack3(f0.w, f1.x, f1.y);
            pk.u2[2] = pack3(f1.z, f1.w, f2.x);
            pk.u2[3] = pack3(f2.y, f2.z, f2.w);
            sbuf[2 * m + 0] = pk.u4[0];
            sbuf[2 * m + 1] = pk.u4[1];
        }
    }
    __syncthreads();

    // ---- prefetch intensity rows 0,1; pack to fp16 pairs on arrival ------
    // i01[4j+p] = h2(i0,i1) for point 4*(tid+j*512)+p  (32 VGPRs, not 64)
    const float4* iv = (const float4*)(intensity + (size_t)b * 3 * PN);
    unsigned i01[32];
#pragma unroll
    for (int j = 0; j < 8; ++j) {
        const float4 f0 = iv[tid + j * 512];          // row 0
        const float4 f1 = iv[4096 + tid + j * 512];   // row 1
        i01[4 * j + 0] = packh2(f0.x, f1.x);
        i01[4 * j + 1] = packh2(f0.y, f1.y);
        i01[4 * j + 2] = packh2(f0.z, f1.z);
        i01[4 * j + 3] = packh2(f0.w, f1.w);
    }

    // ---- phase 1: all 32 e_k, straight-line, no guards ----
    float ev[32];
    float s = 0.f;
#pragma unroll
    for (int k = 0; k < PK; ++k) {
        const uint2 xz = sx[idxs[k]];
        const float2 nxy = __half22float2(*(const __half2*)&xz.x);
        const float  nz  = __half2float(*(const __half*)&xz.y);

        const float px = nxy.x - cx;
        const float py = nxy.y - cy;
        const float pz = nz - cz;

        const float g0 = __expf(-2.f * px * px);
        const float g1 = __expf(-2.f * py * py);
        const float g2 = __expf(-2.f * pz * pz);

        float h0 = fmaf(A00, g0, fmaf(A01, g1, fmaf(A02, g2, d0)));
        float h1 = fmaf(A10, g0, fmaf(A11, g1, fmaf(A12, g2, d1)));
        float h2 = fmaf(A20, g0, fmaf(A21, g1, fmaf(A22, g2, d2)));
        h0 = fmaxf(h0, 0.f); h1 = fmaxf(h1, 0.f); h2 = fmaxf(h2, 0.f);
        const float logit = fmaf(w0, h0, fmaf(w1v, h1, fmaf(w2v, h2, bias2)));

        const float e = __expf(logit);
        ev[k] = e;
        s += e;
    }

    // row 2 of intensity (arrives during the barrier drain)
    unsigned i2pk[32];
#pragma unroll
    for (int j = 0; j < 8; ++j) {
        const float4 f2 = iv[8192 + tid + j * 512];
        i2pk[4 * j + 0] = packh2(f2.x, 0.f);
        i2pk[4 * j + 1] = packh2(f2.y, 0.f);
        i2pk[4 * j + 2] = packh2(f2.z, 0.f);
        i2pk[4 * j + 3] = packh2(f2.w, 0.f);
    }

    __syncthreads();   // everyone done reading xyz from LDS

    // ---- stage 2: intensity (pre-packed regs) -> LDS ----
#pragma unroll
    for (int j = 0; j < 8; ++j) {
        const int m = tid + j * 512;
        uint4 wA, wB;
        wA.x = i01[4 * j + 0]; wA.y = i2pk[4 * j + 0];
        wA.z = i01[4 * j + 1]; wA.w = i2pk[4 * j + 1];
        wB.x = i01[4 * j + 2]; wB.y = i2pk[4 * j + 2];
        wB.z = i01[4 * j + 3]; wB.w = i2pk[4 * j + 3];
        sbuf[2 * m + 0] = wA;
        sbuf[2 * m + 1] = wB;
    }
    __syncthreads();

    // ---- phase 2: weighted intensity accumulate ----
    float a0 = 0.f, a1 = 0.f, a2 = 0.f;
#pragma unroll
    for (int k = 0; k < PK; ++k) {
        const uint2 it = sx[idxs[k]];
        const float2 i01v = __half22float2(*(const __half2*)&it.x);
        const float  i2v  = __half2float(*(const __half*)&it.y);
        const float e = ev[k];
        a0 = fmaf(e, i01v.x, a0);
        a1 = fmaf(e, i01v.y, a1);
        a2 = fmaf(e, i2v,  a2);
    }

    // coalesced per-channel stores
    const float inv = 1.f / s;
    float* ob = out + (size_t)b * 3 * PN;
    ob[0 * PN + n] = a0 * inv;
    ob[1 * PN + n] = a1 * inv;
    ob[2 * PN + n] = a2 * inv;
}

extern "C" void kernel_launch(void* const* d_in, const int* in_sizes, int n_in,
                              void* d_out, int out_size, void* d_ws, size_t ws_size,
                              hipStream_t stream) {
    const float* xyz       = (const float*)d_in[0];
    const float* intensity = (const float*)d_in[1];
    const int*   indices   = (const int*)d_in[2];
    const float* w1        = (const float*)d_in[3];
    const float* b1        = (const float*)d_in[4];
    const float* gamma_    = (const float*)d_in[5];
    const float* beta_     = (const float*)d_in[6];
    const float* mean_     = (const float*)d_in[7];
    const float* var_      = (const float*)d_in[8];
    const float* w2        = (const float*)d_in[9];
    const float* b2        = (const float*)d_in[10];
    float* out = (float*)d_out;

    const int points = PB * PN;   // 131072
    // 256 blocks x 512 threads (1 WG/CU); blockIdx&7 = batch = XCD
    sa_fused<<<points / 512, 512, 0, stream>>>(xyz, intensity, indices,
                                               w1, b1, gamma_, beta_, mean_,
                                               var_, w2, b2, out);
}